// Round 1
// baseline (2032.755 us; speedup 1.0000x reference)
//
#include <hip/hip_runtime.h>

// convex upsample (RAFT-style), fully fused single kernel, fp32.
// depth (8,128,416) f32; feat (8,64,128,416) f32; w1 (64,64,3,3); w2 (144,64,1,1)
// out (8,512,1664) f32.
//
// Block = 256 threads, tile = 8x16 pixels.
// Phase 1: conv3x3+relu, feat+w1 staged in LDS (8-ic chunks), thread = 4px x 8oc.
// Phase 2: h -> LDS -> regs; conv1x1 (w2 via wave-uniform scalar loads), softmax
//          over 9 taps per (sy,sx), convex combine of depth patches, shuffle out.

#define TH 8
#define TW 16
#define ICC 8

__global__ __launch_bounds__(256, 2) void convex_up_fused(
    const float* __restrict__ depth, const float* __restrict__ feat,
    const float* __restrict__ w1, const float* __restrict__ w2,
    float* __restrict__ out)
{
    constexpr int C = 64, H = 128, W = 416;
    constexpr int OW = W * 4;            // 1664
    constexpr int SFP = 20;              // padded feat-tile row stride (floats)
    constexpr int SHP = 66;              // padded h-tile row stride (floats)

    const int tid = threadIdx.x;
    const int bw = blockIdx.x, bh = blockIdx.y, b = blockIdx.z;
    const int h0 = bh * TH, w0 = bw * TW;

    __shared__ float sD[(TH + 2) * (TW + 2)];          // 180 floats: depth + halo
    __shared__ __align__(16) float sU[128 * SHP];      // 8448-float union
    float* sF = sU;            // phase1: [ICC][10][20] = 1600
    float* sW = sU + 1600;     // phase1: [64][ICC][12] = 6144
    float* sH = sU;            // phase2: [128][66]     = 8448

    // ---- stage depth tile (with halo, zero-pad) ----
    if (tid < (TH + 2) * (TW + 2)) {
        int lr = tid / (TW + 2), lc = tid % (TW + 2);
        int gh = h0 - 1 + lr, gw = w0 - 1 + lc;
        float v = 0.f;
        if ((unsigned)gh < (unsigned)H && (unsigned)gw < (unsigned)W)
            v = depth[((size_t)b * H + gh) * W + gw];
        sD[tid] = v;
    }

    // ---- phase 1: conv3x3 + relu ----
    const int quad = tid & 31;       // pixel quad id (32 quads of 4 px)
    const int ocg  = tid >> 5;       // 0..7 (8 oc per group)
    const int pr   = quad >> 2;      // 0..7 tile row
    const int pc   = (quad & 3) * 4; // 0,4,8,12 tile col base

    float acc[4][8];
    #pragma unroll
    for (int j = 0; j < 4; ++j)
        #pragma unroll
        for (int o = 0; o < 8; ++o) acc[j][o] = 0.f;

    for (int icc = 0; icc < C / ICC; ++icc) {
        __syncthreads();   // previous chunk fully consumed before overwrite
        // stage feat chunk: sF[ic][lr][lc], lc<18 valid, global = (h0-1+lr, w0-1+lc)
        for (int idx = tid; idx < ICC * 10 * SFP; idx += 256) {
            int ic  = idx / (10 * SFP);
            int rem = idx - ic * (10 * SFP);
            int lr  = rem / SFP, lc = rem - lr * SFP;
            float v = 0.f;
            if (lc < TW + 2) {
                int gh = h0 - 1 + lr, gw = w0 - 1 + lc;
                if ((unsigned)gh < (unsigned)H && (unsigned)gw < (unsigned)W)
                    v = feat[(((size_t)b * C + (icc * ICC + ic)) * H + gh) * W + gw];
            }
            sF[idx] = v;
        }
        // stage w1 chunk: sW[oc][ic][k], padded to 12 (k<9 valid)
        for (int idx = tid; idx < 64 * ICC * 12; idx += 256) {
            int oc  = idx / (ICC * 12);
            int rem = idx - oc * (ICC * 12);
            int ic  = rem / 12, k = rem - ic * 12;
            float v = 0.f;
            if (k < 9)
                v = w1[((size_t)oc * C + (icc * ICC + ic)) * 9 + k];
            sW[idx] = v;
        }
        __syncthreads();

        #pragma unroll
        for (int ic = 0; ic < ICC; ++ic) {
            float f[3][6];
            #pragma unroll
            for (int dy = 0; dy < 3; ++dy) {
                const float* p = &sF[ic * (10 * SFP) + (pr + dy) * SFP + pc];
                float4 v4 = *(const float4*)p;
                float2 v2 = *(const float2*)(p + 4);
                f[dy][0] = v4.x; f[dy][1] = v4.y; f[dy][2] = v4.z; f[dy][3] = v4.w;
                f[dy][4] = v2.x; f[dy][5] = v2.y;
            }
            #pragma unroll
            for (int o = 0; o < 8; ++o) {
                const float* wp = &sW[((ocg * 8 + o) * ICC + ic) * 12];
                float4 wa = *(const float4*)wp;        // k0..3
                float4 wb = *(const float4*)(wp + 4);  // k4..7
                float w8  = wp[8];                     // k8
                #pragma unroll
                for (int j = 0; j < 4; ++j) {
                    float s = acc[j][o];
                    s += wa.x * f[0][j]     + wa.y * f[0][j + 1] + wa.z * f[0][j + 2];
                    s += wa.w * f[1][j]     + wb.x * f[1][j + 1] + wb.y * f[1][j + 2];
                    s += wb.z * f[2][j]     + wb.w * f[2][j + 1] + w8   * f[2][j + 2];
                    acc[j][o] = s;
                }
            }
        }
    }

    __syncthreads();   // done reading sF/sW (union with sH)

    // relu(h) -> sH[px][oc]
    #pragma unroll
    for (int j = 0; j < 4; ++j) {
        int px = pr * TW + pc + j;
        #pragma unroll
        for (int o = 0; o < 8; o += 2) {
            float2 v;
            v.x = fmaxf(acc[j][o],     0.f);
            v.y = fmaxf(acc[j][o + 1], 0.f);
            *(float2*)&sH[px * SHP + ocg * 8 + o] = v;
        }
    }
    __syncthreads();

    // ---- phase 2: conv1x1 + softmax(9 taps) + convex combine + pixel shuffle ----
    const int px    = tid & 127;
    const int shalf = __builtin_amdgcn_readfirstlane(tid >> 7);  // wave-uniform
    const int r  = px >> 4, cc = px & 15;

    float hreg[64];
    #pragma unroll
    for (int c = 0; c < 64; c += 2) {
        float2 v = *(const float2*)&sH[px * SHP + c];
        hreg[c] = v.x; hreg[c + 1] = v.y;
    }

    float patch[9];
    #pragma unroll
    for (int ky = 0; ky < 3; ++ky)
        #pragma unroll
        for (int kx = 0; kx < 3; ++kx)
            patch[ky * 3 + kx] = sD[(r + ky) * (TW + 2) + (cc + kx)];

    const int gh = h0 + r, gw = w0 + cc;
    float* outp = out + (size_t)b * (H * 4) * OW;

    for (int si = 0; si < 8; ++si) {
        int s = shalf * 8 + si;   // (sy*4+sx) index, uniform per wave
        float lg[9];
        #pragma unroll
        for (int tap = 0; tap < 9; ++tap) {
            const float* wrow = w2 + (size_t)(tap * 16 + s) * 64;  // uniform addr
            float v = 0.f;
            #pragma unroll
            for (int c = 0; c < 64; ++c) v += wrow[c] * hreg[c];
            lg[tap] = v;
        }
        float m = lg[0];
        #pragma unroll
        for (int tap = 1; tap < 9; ++tap) m = fmaxf(m, lg[tap]);
        float sum = 0.f, accv = 0.f;
        #pragma unroll
        for (int tap = 0; tap < 9; ++tap) {
            float e = __expf(lg[tap] - m);
            sum  += e;
            accv += e * patch[tap];
        }
        int sy = s >> 2, sx = s & 3;
        outp[(size_t)(gh * 4 + sy) * OW + (gw * 4 + sx)] = accv / sum;
    }
}

extern "C" void kernel_launch(void* const* d_in, const int* in_sizes, int n_in,
                              void* d_out, int out_size, void* d_ws, size_t ws_size,
                              hipStream_t stream) {
    const float* depth = (const float*)d_in[0];
    const float* feat  = (const float*)d_in[1];
    const float* w1    = (const float*)d_in[2];
    const float* w2    = (const float*)d_in[3];
    float* out = (float*)d_out;

    dim3 grid(416 / TW, 128 / TH, 8);   // 26 x 16 x 8 = 3328 blocks
    dim3 block(256);
    convex_up_fused<<<grid, block, 0, stream>>>(depth, feat, w1, w2, out);
}

// Round 2
// 327.346 us; speedup vs baseline: 6.2098x; 6.2098x over previous
//
#include <hip/hip_runtime.h>

// Convex upsample, fused bf16-MFMA implicit GEMM.
// depth (8,128,416) f32; feat (8,64,128,416) f32; w1 (64,64,3,3) f32; w2 (144,64,1,1) f32
// out (8,512,1664) f32.
//
// prep kernel: w1 -> ws as bf16 [tap][kh][q][oc64][8]  (B-frag contiguous per wave load)
//              w2 -> ws as bf16 [kh][q][ch144][8]
// main kernel: block = 256 thr (4 waves), tile = 8 rows x 16 cols of px.
//   GEMM1: h[64oc] = conv3x3(feat,w1), M=128px N=64 K=576 via mfma_f32_16x16x32_bf16.
//          feat tile staged once in LDS [icg][10][18][8] bf16; B-frags direct from L2.
//   relu+cvt -> per-wave LDS slice sH[32px][72] (A-layout for GEMM2; no barrier needed).
//   GEMM2: logits, M=32px/wave N=144 K=64; n-tile == tap, lane&15 == s
//          -> softmax over 9 taps fully in registers; convex-combine depth patches.
//   Output staged per-wave in LDS, stored as 8 rows x 256 B contiguous float4.

using frag_ab = __attribute__((ext_vector_type(8))) short;   // 8 bf16
using frag_cd = __attribute__((ext_vector_type(4))) float;   // 4 f32

static __device__ __forceinline__ unsigned short f2bf(float f) {
    unsigned u = __builtin_bit_cast(unsigned, f);
    u += 0x7fff + ((u >> 16) & 1);          // round-to-nearest-even
    return (unsigned short)(u >> 16);
}

__global__ void prep_weights(const float* __restrict__ w1, const float* __restrict__ w2,
                             unsigned short* __restrict__ w1bf, unsigned short* __restrict__ w2bf) {
    int i = blockIdx.x * 256 + threadIdx.x;
    if (i < 36864) {   // ((tap*2+kh)*4+q)*512 + oc*8 + j
        int j = i & 7, oc = (i >> 3) & 63, g = i >> 9;   // g = (tap*2+kh)*4+q
        int q = g & 3, kh = (g >> 2) & 1, tap = g >> 3;
        int ic = kh * 32 + q * 8 + j;
        int ky = tap / 3, kx = tap % 3;
        w1bf[i] = f2bf(w1[(oc * 64 + ic) * 9 + ky * 3 + kx]);
    }
    if (i < 9216) {    // ((kh*4+q)*144 + ch)*8 + j
        int j = i & 7, ch = (i >> 3) % 144, g = (i >> 3) / 144;
        int q = g & 3, kh = g >> 2;
        int ic = kh * 32 + q * 8 + j;
        w2bf[i] = f2bf(w2[ch * 64 + ic]);
    }
}

__global__ __launch_bounds__(256, 3) void convex_up_mfma(
    const float* __restrict__ depth, const float* __restrict__ feat,
    const unsigned short* __restrict__ w1bf, const unsigned short* __restrict__ w2bf,
    float* __restrict__ out)
{
    constexpr int H = 128, W = 416, OW = 1664;

    __shared__ unsigned short sF[8 * 10 * 18 * 8];   // feat tile [icg][row][col][8] = 23040 B
    __shared__ unsigned short sH[4][32 * 72];        // per-wave h bf16 [px32][72]   = 18432 B
    __shared__ float sD[10 * 18];                    // depth tile + halo            =   720 B

    const int tid  = threadIdx.x;
    const int wv   = tid >> 6;
    const int lane = tid & 63;
    const int q    = lane >> 4;       // 0..3
    const int ln   = lane & 15;       // 0..15
    const int bw = blockIdx.x, bh = blockIdx.y, b = blockIdx.z;
    const int h0 = bh * 8, w0 = bw * 16;

    // ---- stage depth tile (halo, zero-pad) ----
    if (tid < 180) {
        int lr = tid / 18, lc = tid % 18;
        int gh = h0 - 1 + lr, gw = w0 - 1 + lc;
        float v = 0.f;
        if ((unsigned)gh < (unsigned)H && (unsigned)gw < (unsigned)W)
            v = depth[((size_t)b * H + gh) * W + gw];
        sD[tid] = v;
    }
    // ---- stage feat tile: 64 ic x 10 x 18, fp32 -> bf16 ----
    for (int idx = tid; idx < 11520; idx += 256) {
        int ic = idx / 180, rem = idx - ic * 180;
        int lr = rem / 18, lc = rem - lr * 18;
        int gh = h0 - 1 + lr, gw = w0 - 1 + lc;
        float v = 0.f;
        if ((unsigned)gh < (unsigned)H && (unsigned)gw < (unsigned)W)
            v = feat[(((size_t)b * 64 + ic) * H + gh) * W + gw];
        sF[(((ic >> 3) * 10 + lr) * 18 + lc) * 8 + (ic & 7)] = f2bf(v);
    }
    __syncthreads();   // the only block-wide barrier

    // ---- GEMM1: h = conv3x3, wave wv owns px rows 2wv, 2wv+1 (32 px) x 64 oc ----
    frag_cd acc1[2][4];
    #pragma unroll
    for (int mt = 0; mt < 2; ++mt)
        #pragma unroll
        for (int nt = 0; nt < 4; ++nt) acc1[mt][nt] = frag_cd{0.f, 0.f, 0.f, 0.f};

    #pragma unroll
    for (int tap = 0; tap < 9; ++tap) {
        const int ky = tap / 3, kx = tap % 3;
        #pragma unroll
        for (int kh = 0; kh < 2; ++kh) {
            frag_ab a[2];
            #pragma unroll
            for (int mt = 0; mt < 2; ++mt) {
                int row = 2 * wv + mt + ky, col = ln + kx;
                a[mt] = *(const frag_ab*)&sF[(((kh * 4 + q) * 10 + row) * 18 + col) * 8];
            }
            frag_ab bf[4];
            #pragma unroll
            for (int nt = 0; nt < 4; ++nt)
                bf[nt] = *(const frag_ab*)&w1bf[(size_t)((tap * 2 + kh) * 4 + q) * 512 + (nt * 16 + ln) * 8];
            #pragma unroll
            for (int mt = 0; mt < 2; ++mt)
                #pragma unroll
                for (int nt = 0; nt < 4; ++nt)
                    acc1[mt][nt] = __builtin_amdgcn_mfma_f32_16x16x32_bf16(a[mt], bf[nt], acc1[mt][nt], 0, 0, 0);
        }
    }

    // ---- relu + cvt -> sH[wv] in GEMM2-A layout [px_loc][oc] (stride 72) ----
    #pragma unroll
    for (int mt = 0; mt < 2; ++mt)
        #pragma unroll
        for (int nt = 0; nt < 4; ++nt)
            #pragma unroll
            for (int r = 0; r < 4; ++r)
                sH[wv][(mt * 16 + q * 4 + r) * 72 + nt * 16 + ln] =
                    f2bf(fmaxf(acc1[mt][nt][r], 0.f));
    // same-wave LDS RAW: compiler inserts lgkmcnt; no __syncthreads needed

    // ---- GEMM2: logits[144] per px; n-tile index == tap ----
    frag_cd acc2[2][9];
    #pragma unroll
    for (int mt = 0; mt < 2; ++mt)
        #pragma unroll
        for (int nt = 0; nt < 9; ++nt) acc2[mt][nt] = frag_cd{0.f, 0.f, 0.f, 0.f};

    #pragma unroll
    for (int kh = 0; kh < 2; ++kh) {
        frag_ab a2[2];
        #pragma unroll
        for (int mt = 0; mt < 2; ++mt)
            a2[mt] = *(const frag_ab*)&sH[wv][(mt * 16 + ln) * 72 + kh * 32 + q * 8];
        #pragma unroll
        for (int nt = 0; nt < 9; ++nt) {
            frag_ab b2 = *(const frag_ab*)&w2bf[(size_t)((kh * 4 + q) * 144 + nt * 16 + ln) * 8];
            acc2[0][nt] = __builtin_amdgcn_mfma_f32_16x16x32_bf16(a2[0], b2, acc2[0][nt], 0, 0, 0);
            acc2[1][nt] = __builtin_amdgcn_mfma_f32_16x16x32_bf16(a2[1], b2, acc2[1][nt], 0, 0, 0);
        }
    }

    // ---- softmax over 9 taps in registers + convex combine; stage to sOut ----
    float* sOutw = (float*)&sH[wv][0];   // overlay own slice (reads done): [px32][17] f32
    const int s_ = ln;                   // s = sy*4+sx
    #pragma unroll
    for (int mt = 0; mt < 2; ++mt) {
        const int prow = 2 * wv + mt;    // tile row of these px
        #pragma unroll
        for (int r = 0; r < 4; ++r) {
            const int pcol = q * 4 + r;
            float lg[9];
            #pragma unroll
            for (int t = 0; t < 9; ++t) lg[t] = acc2[mt][t][r];
            float mx = lg[0];
            #pragma unroll
            for (int t = 1; t < 9; ++t) mx = fmaxf(mx, lg[t]);
            float sum = 0.f, up = 0.f;
            #pragma unroll
            for (int t = 0; t < 9; ++t) {
                float e = __expf(lg[t] - mx);
                sum += e;
                up  += e * sD[(prow + t / 3) * 18 + (pcol + t % 3)];
            }
            sOutw[(mt * 16 + pcol) * 17 + s_] = up / sum;
        }
    }
    // same-wave LDS RAW again; then fully-coalesced store: 8 rows x 256 B per wave
    float* outb = out + (size_t)b * 512 * OW + (size_t)(h0 + 2 * wv) * 4 * OW + w0 * 4;
    const int row_o = lane >> 3;          // 0..7: mt = row_o>>2, sy = row_o&3
    const int mt_o  = row_o >> 2, sy_o = row_o & 3;
    #pragma unroll
    for (int v = 0; v < 2; ++v) {
        float4 o;
        #pragma unroll
        for (int e = 0; e < 4; ++e) {
            int j = (lane & 7) * 8 + v * 4 + e;       // 0..63 within out row
            o[e] = sOutw[(mt_o * 16 + (j >> 2)) * 17 + sy_o * 4 + (j & 3)];
        }
        *(float4*)&outb[(size_t)row_o * OW + (lane & 7) * 8 + v * 4] = o;
    }
}

extern "C" void kernel_launch(void* const* d_in, const int* in_sizes, int n_in,
                              void* d_out, int out_size, void* d_ws, size_t ws_size,
                              hipStream_t stream) {
    const float* depth = (const float*)d_in[0];
    const float* feat  = (const float*)d_in[1];
    const float* w1    = (const float*)d_in[2];
    const float* w2    = (const float*)d_in[3];
    float* out = (float*)d_out;

    unsigned short* w1bf = (unsigned short*)d_ws;            // 36864 bf16
    unsigned short* w2bf = w1bf + 36864;                     //  9216 bf16

    prep_weights<<<144, 256, 0, stream>>>(w1, w2, w1bf, w2bf);
    dim3 grid(416 / 16, 128 / 8, 8);   // 26 x 16 x 8 = 3328 blocks
    convex_up_mfma<<<grid, dim3(256), 0, stream>>>(depth, feat, w1bf, w2bf, out);
}

// Round 3
// 239.792 us; speedup vs baseline: 8.4772x; 1.3651x over previous
//
#include <hip/hip_runtime.h>

// Convex upsample, fused bf16-MFMA implicit GEMM, round 3.
// Path A (ws >= ~55.75 MB):
//   prep:   w1/w2 -> bf16 frag layouts; zero the NHWC pad ring.
//   nchw_to_nhwc: feat NCHW f32 -> zero-padded NHWC bf16 [b][130][418][64] in ws.
//   main:   feat tile staged via global_load_lds dwordx4 (contig 2304 B/row, no
//           bounds logic), XOR-swizzled ic-chunks for conflict-free ds_read_b128;
//           GEMM1 (conv3x3) -> relu -> sH overlay on sF (barrier) -> GEMM2 (1x1,
//           n-tile==tap) -> register softmax over 9 taps -> convex combine ->
//           coalesced pixel-shuffled store.
// Path B (small ws): round-2 kernel (self-staged f32), known-good fallback.

using frag_ab = __attribute__((ext_vector_type(8))) short;   // 8 bf16
using frag_cd = __attribute__((ext_vector_type(4))) float;   // 4 f32
typedef __attribute__((ext_vector_type(8))) unsigned short ushort8;

static __device__ __forceinline__ unsigned short f2bf(float f) {
    unsigned u = __builtin_bit_cast(unsigned, f);
    u += 0x7fff + ((u >> 16) & 1);          // round-to-nearest-even
    return (unsigned short)(u >> 16);
}

// ---------------- prep: weights + NHWC pad ring ----------------
__global__ void prep(const float* __restrict__ w1, const float* __restrict__ w2,
                     unsigned short* __restrict__ w1bf, unsigned short* __restrict__ w2bf,
                     unsigned short* __restrict__ nhwc, int do_pad) {
    int i = blockIdx.x * 256 + threadIdx.x;
    if (i < 36864) {   // ((tap*2+kh)*4+q)*512 + oc*8 + j
        int j = i & 7, oc = (i >> 3) & 63, g = i >> 9;
        int q = g & 3, kh = (g >> 2) & 1, tap = g >> 3;
        int ic = kh * 32 + q * 8 + j;
        w1bf[i] = f2bf(w1[(oc * 64 + ic) * 9 + (tap / 3) * 3 + (tap % 3)]);
    }
    if (i < 9216) {    // ((kh*4+q)*144 + ch)*8 + j
        int j = i & 7, ch = (i >> 3) % 144, g = (i >> 3) / 144;
        int q = g & 3, kh = g >> 2;
        w2bf[i] = f2bf(w2[ch * 64 + (kh * 32 + q * 8 + j)]);
    }
    if (do_pad && i < 69888) {   // zero pad ring: rows {0,129} all w; cols {0,417} rows 1..128
        int b = i / 8736, rem = i - b * 8736;
        int pos = rem >> 3, pack = rem & 7;
        int row, w;
        if (pos < 836) { row = (pos < 418) ? 0 : 129; w = (pos < 418) ? pos : pos - 418; }
        else           { int t = pos - 836; row = 1 + (t >> 1); w = (t & 1) ? 417 : 0; }
        ushort8 z = {0, 0, 0, 0, 0, 0, 0, 0};
        *(ushort8*)&nhwc[(((size_t)b * 130 + row) * 418 + w) * 64 + pack * 8] = z;
    }
}

// ---------------- feat NCHW f32 -> padded NHWC bf16 ----------------
__global__ __launch_bounds__(256, 8) void nchw_to_nhwc(const float* __restrict__ feat,
                                                       unsigned short* __restrict__ nhwc) {
    __shared__ unsigned short sT[32 * 64];   // [w][c]
    const int b = blockIdx.z, h = blockIdx.y, w0 = blockIdx.x * 32;
    const int tid = threadIdx.x;
    const int c = tid >> 2, j = tid & 3;     // 8 w-elements per thread
    const float* src = feat + (((size_t)b * 64 + c) * 128 + h) * 416 + w0 + j * 8;
    float4 v0 = *(const float4*)src;
    float4 v1 = *(const float4*)(src + 4);
    sT[(j * 8 + 0) * 64 + c] = f2bf(v0.x);
    sT[(j * 8 + 1) * 64 + c] = f2bf(v0.y);
    sT[(j * 8 + 2) * 64 + c] = f2bf(v0.z);
    sT[(j * 8 + 3) * 64 + c] = f2bf(v0.w);
    sT[(j * 8 + 4) * 64 + c] = f2bf(v1.x);
    sT[(j * 8 + 5) * 64 + c] = f2bf(v1.y);
    sT[(j * 8 + 6) * 64 + c] = f2bf(v1.z);
    sT[(j * 8 + 7) * 64 + c] = f2bf(v1.w);
    __syncthreads();
    const int w = tid >> 3, pack = tid & 7;
    ushort8 val = *(ushort8*)&sT[w * 64 + pack * 8];
    *(ushort8*)&nhwc[(((size_t)b * 130 + h + 1) * 418 + (w0 + w + 1)) * 64 + pack * 8] = val;
}

// ---------------- main fused kernel (path A) ----------------
__global__ __launch_bounds__(256, 4) void convex_up_mfma2(
    const float* __restrict__ depth, const unsigned short* __restrict__ nhwc,
    const unsigned short* __restrict__ w1bf, const unsigned short* __restrict__ w2bf,
    float* __restrict__ out)
{
    constexpr int H = 128, W = 416, OW = 1664;
    constexpr int RS = 418 * 64;              // padded NHWC row stride (ushorts)

    __shared__ __align__(16) unsigned short sF[1440 * 8];   // 23040 B: [r10][col18][icc8 swz][8]
    __shared__ float sD[180];

    const int tid  = threadIdx.x;
    const int wv   = tid >> 6;
    const int lane = tid & 63;
    const int q    = lane >> 4;
    const int ln   = lane & 15;
    const int bw = blockIdx.x, bh = blockIdx.y, b = blockIdx.z;
    const int h0 = bh * 8, w0 = bw * 16;

    // depth tile (halo, zero-pad)
    if (tid < 180) {
        int lr = tid / 18, lc = tid % 18;
        int gh = h0 - 1 + lr, gw = w0 - 1 + lc;
        float v = 0.f;
        if ((unsigned)gh < (unsigned)H && (unsigned)gw < (unsigned)W)
            v = depth[((size_t)b * H + gh) * W + gw];
        sD[tid] = v;
    }

    // feat tile: 1440 16B-chunks via global_load_lds (LDS chunk c = (r*18+col)*8 + icc_swz)
    const unsigned short* gbase = nhwc + ((size_t)(b * 130 + h0) * 418 + w0) * 64;
    #pragma unroll
    for (int k = 0; k < 6; ++k) {
        int i = wv + 4 * k;
        int c = i * 64 + lane;
        if (c < 1440) {
            int r = c / 144, m = c - r * 144;
            int col = m >> 3, iccs = m & 7;
            int icc = iccs ^ (col & 7);       // XOR swizzle (source side)
            const unsigned short* g = gbase + (size_t)r * RS + col * 64 + icc * 8;
            __builtin_amdgcn_global_load_lds((const __attribute__((address_space(1))) void*)g,
                                             (__attribute__((address_space(3))) void*)&sF[c * 8],
                                             16, 0, 0);
        }
    }
    __syncthreads();

    // ---- GEMM1: conv3x3, wave owns px rows 2wv,2wv+1 x 64 oc ----
    frag_cd acc1[2][4];
    #pragma unroll
    for (int mt = 0; mt < 2; ++mt)
        #pragma unroll
        for (int nt = 0; nt < 4; ++nt) acc1[mt][nt] = frag_cd{0.f, 0.f, 0.f, 0.f};

    #pragma unroll
    for (int tap = 0; tap < 9; ++tap) {
        const int ky = tap / 3, kx = tap % 3;
        #pragma unroll
        for (int kh = 0; kh < 2; ++kh) {
            frag_ab a[2];
            #pragma unroll
            for (int mt = 0; mt < 2; ++mt) {
                int r = 2 * wv + mt + ky, col = ln + kx;
                int slot = (r * 18 + col) * 8 + ((kh * 4 + q) ^ (col & 7));
                a[mt] = *(const frag_ab*)&sF[slot * 8];
            }
            frag_ab bf[4];
            #pragma unroll
            for (int nt = 0; nt < 4; ++nt)
                bf[nt] = *(const frag_ab*)&w1bf[(size_t)((tap * 2 + kh) * 4 + q) * 512 + (nt * 16 + ln) * 8];
            #pragma unroll
            for (int mt = 0; mt < 2; ++mt)
                #pragma unroll
                for (int nt = 0; nt < 4; ++nt)
                    acc1[mt][nt] = __builtin_amdgcn_mfma_f32_16x16x32_bf16(a[mt], bf[nt], acc1[mt][nt], 0, 0, 0);
        }
    }

    __syncthreads();   // all waves done reading sF; overlay sH on it

    unsigned short* sH = sF + wv * 2304;   // per-wave [px32][72] bf16 (4608 B slice)
    #pragma unroll
    for (int mt = 0; mt < 2; ++mt)
        #pragma unroll
        for (int nt = 0; nt < 4; ++nt)
            #pragma unroll
            for (int r = 0; r < 4; ++r)
                sH[(mt * 16 + q * 4 + r) * 72 + nt * 16 + ln] = f2bf(fmaxf(acc1[mt][nt][r], 0.f));
    // same-wave LDS RAW: compiler-inserted lgkmcnt, no barrier needed

    // ---- GEMM2: logits, n-tile == tap ----
    frag_cd acc2[2][9];
    #pragma unroll
    for (int mt = 0; mt < 2; ++mt)
        #pragma unroll
        for (int nt = 0; nt < 9; ++nt) acc2[mt][nt] = frag_cd{0.f, 0.f, 0.f, 0.f};

    #pragma unroll
    for (int kh = 0; kh < 2; ++kh) {
        frag_ab a2[2];
        #pragma unroll
        for (int mt = 0; mt < 2; ++mt)
            a2[mt] = *(const frag_ab*)&sH[(mt * 16 + ln) * 72 + kh * 32 + q * 8];
        #pragma unroll
        for (int nt = 0; nt < 9; ++nt) {
            frag_ab b2 = *(const frag_ab*)&w2bf[(size_t)((kh * 4 + q) * 144 + nt * 16 + ln) * 8];
            acc2[0][nt] = __builtin_amdgcn_mfma_f32_16x16x32_bf16(a2[0], b2, acc2[0][nt], 0, 0, 0);
            acc2[1][nt] = __builtin_amdgcn_mfma_f32_16x16x32_bf16(a2[1], b2, acc2[1][nt], 0, 0, 0);
        }
    }

    // ---- softmax over 9 taps + convex combine; stage into own slice ----
    float* sOutw = (float*)sH;   // [px32][17] f32, 2168 floats < slice capacity 1152*... (4608 B = 1152 f32; idx max 542) OK
    #pragma unroll
    for (int mt = 0; mt < 2; ++mt) {
        const int prow = 2 * wv + mt;
        #pragma unroll
        for (int r = 0; r < 4; ++r) {
            const int pcol = q * 4 + r;
            float lg[9];
            #pragma unroll
            for (int t = 0; t < 9; ++t) lg[t] = acc2[mt][t][r];
            float mx = lg[0];
            #pragma unroll
            for (int t = 1; t < 9; ++t) mx = fmaxf(mx, lg[t]);
            float sum = 0.f, up = 0.f;
            #pragma unroll
            for (int t = 0; t < 9; ++t) {
                float e = __expf(lg[t] - mx);
                sum += e;
                up  += e * sD[(prow + t / 3) * 18 + (pcol + t % 3)];
            }
            sOutw[(mt * 16 + pcol) * 17 + ln] = up / sum;
        }
    }
    float* outb = out + (size_t)b * 512 * OW + (size_t)(h0 + 2 * wv) * 4 * OW + w0 * 4;
    const int row_o = lane >> 3;
    const int mt_o  = row_o >> 2, sy_o = row_o & 3;
    #pragma unroll
    for (int v = 0; v < 2; ++v) {
        float4 o;
        #pragma unroll
        for (int e = 0; e < 4; ++e) {
            int j = (lane & 7) * 8 + v * 4 + e;
            o[e] = sOutw[(mt_o * 16 + (j >> 2)) * 17 + sy_o * 4 + (j & 3)];
        }
        *(float4*)&outb[(size_t)row_o * OW + (lane & 7) * 8 + v * 4] = o;
    }
}

// ---------------- fallback (round-2 kernel, self-staged) ----------------
__global__ __launch_bounds__(256, 3) void convex_up_mfma_fb(
    const float* __restrict__ depth, const float* __restrict__ feat,
    const unsigned short* __restrict__ w1bf, const unsigned short* __restrict__ w2bf,
    float* __restrict__ out)
{
    constexpr int H = 128, W = 416, OW = 1664;
    __shared__ unsigned short sF[8 * 10 * 18 * 8];
    __shared__ unsigned short sH[4][32 * 72];
    __shared__ float sD[10 * 18];
    const int tid = threadIdx.x, wv = tid >> 6, lane = tid & 63;
    const int q = lane >> 4, ln = lane & 15;
    const int bw = blockIdx.x, bh = blockIdx.y, b = blockIdx.z;
    const int h0 = bh * 8, w0 = bw * 16;
    if (tid < 180) {
        int lr = tid / 18, lc = tid % 18;
        int gh = h0 - 1 + lr, gw = w0 - 1 + lc;
        float v = 0.f;
        if ((unsigned)gh < (unsigned)H && (unsigned)gw < (unsigned)W)
            v = depth[((size_t)b * H + gh) * W + gw];
        sD[tid] = v;
    }
    for (int idx = tid; idx < 11520; idx += 256) {
        int ic = idx / 180, rem = idx - ic * 180;
        int lr = rem / 18, lc = rem - lr * 18;
        int gh = h0 - 1 + lr, gw = w0 - 1 + lc;
        float v = 0.f;
        if ((unsigned)gh < (unsigned)H && (unsigned)gw < (unsigned)W)
            v = feat[(((size_t)b * 64 + ic) * H + gh) * W + gw];
        sF[(((ic >> 3) * 10 + lr) * 18 + lc) * 8 + (ic & 7)] = f2bf(v);
    }
    __syncthreads();
    frag_cd acc1[2][4];
    for (int mt = 0; mt < 2; ++mt) for (int nt = 0; nt < 4; ++nt) acc1[mt][nt] = frag_cd{0.f,0.f,0.f,0.f};
    #pragma unroll
    for (int tap = 0; tap < 9; ++tap) {
        const int ky = tap / 3, kx = tap % 3;
        #pragma unroll
        for (int kh = 0; kh < 2; ++kh) {
            frag_ab a[2];
            #pragma unroll
            for (int mt = 0; mt < 2; ++mt)
                a[mt] = *(const frag_ab*)&sF[(((kh * 4 + q) * 10 + 2 * wv + mt + ky) * 18 + ln + kx) * 8];
            frag_ab bf[4];
            #pragma unroll
            for (int nt = 0; nt < 4; ++nt)
                bf[nt] = *(const frag_ab*)&w1bf[(size_t)((tap * 2 + kh) * 4 + q) * 512 + (nt * 16 + ln) * 8];
            #pragma unroll
            for (int mt = 0; mt < 2; ++mt)
                #pragma unroll
                for (int nt = 0; nt < 4; ++nt)
                    acc1[mt][nt] = __builtin_amdgcn_mfma_f32_16x16x32_bf16(a[mt], bf[nt], acc1[mt][nt], 0, 0, 0);
        }
    }
    #pragma unroll
    for (int mt = 0; mt < 2; ++mt)
        #pragma unroll
        for (int nt = 0; nt < 4; ++nt)
            #pragma unroll
            for (int r = 0; r < 4; ++r)
                sH[wv][(mt * 16 + q * 4 + r) * 72 + nt * 16 + ln] = f2bf(fmaxf(acc1[mt][nt][r], 0.f));
    frag_cd acc2[2][9];
    for (int mt = 0; mt < 2; ++mt) for (int nt = 0; nt < 9; ++nt) acc2[mt][nt] = frag_cd{0.f,0.f,0.f,0.f};
    #pragma unroll
    for (int kh = 0; kh < 2; ++kh) {
        frag_ab a2[2];
        #pragma unroll
        for (int mt = 0; mt < 2; ++mt)
            a2[mt] = *(const frag_ab*)&sH[wv][(mt * 16 + ln) * 72 + kh * 32 + q * 8];
        #pragma unroll
        for (int nt = 0; nt < 9; ++nt) {
            frag_ab b2 = *(const frag_ab*)&w2bf[(size_t)((kh * 4 + q) * 144 + nt * 16 + ln) * 8];
            acc2[0][nt] = __builtin_amdgcn_mfma_f32_16x16x32_bf16(a2[0], b2, acc2[0][nt], 0, 0, 0);
            acc2[1][nt] = __builtin_amdgcn_mfma_f32_16x16x32_bf16(a2[1], b2, acc2[1][nt], 0, 0, 0);
        }
    }
    float* sOutw = (float*)&sH[wv][0];
    #pragma unroll
    for (int mt = 0; mt < 2; ++mt) {
        const int prow = 2 * wv + mt;
        #pragma unroll
        for (int r = 0; r < 4; ++r) {
            const int pcol = q * 4 + r;
            float lg[9];
            #pragma unroll
            for (int t = 0; t < 9; ++t) lg[t] = acc2[mt][t][r];
            float mx = lg[0];
            #pragma unroll
            for (int t = 1; t < 9; ++t) mx = fmaxf(mx, lg[t]);
            float sum = 0.f, up = 0.f;
            #pragma unroll
            for (int t = 0; t < 9; ++t) {
                float e = __expf(lg[t] - mx);
                sum += e; up += e * sD[(prow + t / 3) * 18 + (pcol + t % 3)];
            }
            sOutw[(mt * 16 + pcol) * 17 + ln] = up / sum;
        }
    }
    float* outb = out + (size_t)b * 512 * OW + (size_t)(h0 + 2 * wv) * 4 * OW + w0 * 4;
    const int row_o = lane >> 3, mt_o = row_o >> 2, sy_o = row_o & 3;
    #pragma unroll
    for (int v = 0; v < 2; ++v) {
        float4 o;
        #pragma unroll
        for (int e = 0; e < 4; ++e) {
            int j = (lane & 7) * 8 + v * 4 + e;
            o[e] = sOutw[(mt_o * 16 + (j >> 2)) * 17 + sy_o * 4 + (j & 3)];
        }
        *(float4*)&outb[(size_t)row_o * OW + (lane & 7) * 8 + v * 4] = o;
    }
}

extern "C" void kernel_launch(void* const* d_in, const int* in_sizes, int n_in,
                              void* d_out, int out_size, void* d_ws, size_t ws_size,
                              hipStream_t stream) {
    const float* depth = (const float*)d_in[0];
    const float* feat  = (const float*)d_in[1];
    const float* w1    = (const float*)d_in[2];
    const float* w2    = (const float*)d_in[3];
    float* out = (float*)d_out;

    const size_t NHWC_USHORTS = (size_t)8 * 130 * 418 * 64;        // 27,827,200
    const size_t NEED = NHWC_USHORTS * 2 + (36864 + 9216) * 2;     // 55,746,560 B

    if (ws_size >= NEED) {
        unsigned short* nhwc = (unsigned short*)d_ws;
        unsigned short* w1bf = nhwc + NHWC_USHORTS;
        unsigned short* w2bf = w1bf + 36864;
        prep<<<273, 256, 0, stream>>>(w1, w2, w1bf, w2bf, nhwc, 1);
        nchw_to_nhwc<<<dim3(13, 128, 8), 256, 0, stream>>>(feat, nhwc);
        convex_up_mfma2<<<dim3(26, 16, 8), dim3(256), 0, stream>>>(depth, nhwc, w1bf, w2bf, out);
    } else {
        unsigned short* w1bf = (unsigned short*)d_ws;
        unsigned short* w2bf = w1bf + 36864;
        prep<<<273, 256, 0, stream>>>(w1, w2, w1bf, w2bf, nullptr, 0);
        convex_up_mfma_fb<<<dim3(26, 16, 8), dim3(256), 0, stream>>>(depth, feat, w1bf, w2bf, out);
    }
}